// Round 14
// baseline (290.815 us; speedup 1.0000x reference)
//
#include <hip/hip_runtime.h>
#include <hip/hip_fp16.h>
#include <math.h>

#define NN 100000
#define EE 3200000
#define ET (EE + NN)
#define BKW 128                       // dsts per bucket
#define NBK ((NN + BKW - 1) / BKW)    // 782 buckets
#define BCAP 5120                     // per-bucket capacity (p2 LDS stage bound)
#define EPB 16384                     // edges per p1 block (two-pass, 196 blocks)
#define NB_P1 ((EE + EPB - 1) / EPB)  // 196
#define TROW (NBK + 1)                // run-table row: 782 excl + total
#define NB_G 391                      // gemm blocks: 391*256 = 100096 >= NN

typedef float v2f __attribute__((ext_vector_type(2)));
typedef float v4f __attribute__((ext_vector_type(4)));
typedef _Float16 v8h __attribute__((ext_vector_type(8)));

__device__ __forceinline__ float lrelu(float v) { return fmaxf(v, 0.2f * v); }

__device__ __forceinline__ unsigned char to_fp8(float v) {
  return (unsigned char)(__builtin_amdgcn_cvt_pk_fp8_f32(v, v, 0, false) & 0xff);
}

// ---------------- Fused: CSR phase-1 (blocks 0..NB_P1-1, two-pass, BLOCK-MAJOR
//                  bbuf: each block scatters only within its own 64 KB segment
//                  -> L2 write-combining -> DRAM sees streaming, no RMW)
//                  + Layer-1 MFMA GEMM (blocks NB_P1..NB_P1+NB_G-1) ----------------
// p1 publishes tbl[blk][bucket] = within-segment exclusive offset (+ total at
// [NBK]) so p2 can gather its bucket's 196 runs (~21 edges each).
// gemm1 D layout (16x16x32): row = (lane>>4)*4 + reg, col = lane&15.

__global__ __launch_bounds__(256) void k_p1g1(
    const int* __restrict__ srcs, const int* __restrict__ dsts,
    int* __restrict__ bcount, int* __restrict__ bbuf, int* __restrict__ tbl,
    const float* __restrict__ x, const float* __restrict__ W1,
    const float* __restrict__ a1d,
    unsigned char* __restrict__ P1, __half* __restrict__ ed1) {
  __shared__ char smem[16 * 64 * 8 * 2];   // 16 KB union
  int tid = threadIdx.x;
  if (blockIdx.x < NB_P1) {
    int* lcnt     = (int*)smem;        // NBK
    int* excl     = lcnt + NBK;        // NBK
    int* cur      = excl + NBK;        // NBK
    int* partials = cur + NBK;         // 256   (total ~10.4 KB < 16 KB)
    int e0 = blockIdx.x * EPB;
    int m = min(EPB, EE - e0);         // 16384 or 5120 (multiples of 16)
    for (int i = tid; i < NBK; i += 256) lcnt[i] = 0;
    __syncthreads();
    // pass A: histogram (dsts only)
    for (int i0 = tid * 16; i0 < m; i0 += 4096) {
      const int4* dp = reinterpret_cast<const int4*>(dsts + e0 + i0);
      int4 d4[4];
#pragma unroll
      for (int j = 0; j < 4; ++j) d4[j] = dp[j];
#pragma unroll
      for (int i = 0; i < 16; ++i)
        atomicAdd(&lcnt[((const int*)d4)[i] >> 7], 1);
    }
    __syncthreads();
    // blocked exclusive scan over NBK buckets (4 buckets/thread)
    int b0 = tid * 4;
    int own = 0;
#pragma unroll
    for (int k = 0; k < 4; ++k) {
      int b = b0 + k;
      if (b < NBK) own += lcnt[b];
    }
    partials[tid] = own;
    __syncthreads();
    for (int off = 1; off < 256; off <<= 1) {
      int v = (tid >= off) ? partials[tid - off] : 0;
      __syncthreads();
      partials[tid] += v;
      __syncthreads();
    }
    int run = partials[tid] - own;
#pragma unroll
    for (int k = 0; k < 4; ++k) {
      int b = b0 + k;
      if (b < NBK) {
        excl[b] = run;
        cur[b] = run;
        run += lcnt[b];
      }
    }
    __syncthreads();
    // publish run table + bucket totals (fire-and-forget adds)
    int trow = blockIdx.x * TROW;
    for (int i = tid; i < NBK; i += 256) {
      tbl[trow + i] = excl[i];
      int c = lcnt[i];
      if (c) atomicAdd(&bcount[i], c);
    }
    if (tid == 0) tbl[trow + NBK] = m;
    // pass C: re-read edges, scatter into OWN 64 KB block segment
    size_t seg = (size_t)blockIdx.x * EPB;
    for (int i0 = tid * 16; i0 < m; i0 += 4096) {
      const int4* dp = reinterpret_cast<const int4*>(dsts + e0 + i0);
      const int4* sp = reinterpret_cast<const int4*>(srcs + e0 + i0);
      int4 d4[4], s4[4];
#pragma unroll
      for (int j = 0; j < 4; ++j) { d4[j] = dp[j]; s4[j] = sp[j]; }
#pragma unroll
      for (int i = 0; i < 16; ++i) {
        int d = ((const int*)d4)[i];
        int s = ((const int*)s4)[i];
        int b = d >> 7;
        int pos = atomicAdd(&cur[b], 1);
        bbuf[seg + pos] = (s << 7) | (d & 127);
      }
    }
    return;
  }
  // ---- gemm1 ----
  _Float16* Wb = (_Float16*)smem;   // 16 KB fragment-major (alias)
  int gbid = blockIdx.x - NB_P1;
  for (int idx = tid; idx < 16 * 64; idx += 256) {
    int f = idx >> 6, l = idx & 63;
    int nt = f >> 2, kk = f & 3;
    int ql = l >> 4, cl = l & 15;
    int col = nt * 16 + cl;
    int k0 = kk * 32 + ql * 8;
    v8h tmp;
#pragma unroll
    for (int j = 0; j < 8; ++j) tmp[j] = (_Float16)W1[(k0 + j) * 64 + col];
    *reinterpret_cast<v8h*>(&Wb[idx * 8]) = tmp;
  }
  __syncthreads();
  int wv = tid >> 6, lane = tid & 63;
  int q = lane >> 4, c = lane & 15;
  v8h bf[16];
#pragma unroll
  for (int f = 0; f < 16; ++f)
    bf[f] = *reinterpret_cast<const v8h*>(&Wb[(f * 64 + lane) * 8]);
  float a1d_l[4];
#pragma unroll
  for (int nt = 0; nt < 4; ++nt) a1d_l[nt] = a1d[nt * 16 + c];
  for (int t = 0; t < 4; ++t) {
    int n0 = gbid * 256 + wv * 64 + t * 16;
    int row = n0 + c;
    row = (row < NN) ? row : (NN - 1);
    v4f acc[4] = {{0.f,0.f,0.f,0.f},{0.f,0.f,0.f,0.f},{0.f,0.f,0.f,0.f},{0.f,0.f,0.f,0.f}};
#pragma unroll
    for (int kk = 0; kk < 4; ++kk) {
      const float* xp = x + (size_t)row * 128 + kk * 32 + q * 8;
      float4 x0 = *reinterpret_cast<const float4*>(xp);
      float4 x1 = *reinterpret_cast<const float4*>(xp + 4);
      v8h af;
      af[0] = (_Float16)x0.x; af[1] = (_Float16)x0.y;
      af[2] = (_Float16)x0.z; af[3] = (_Float16)x0.w;
      af[4] = (_Float16)x1.x; af[5] = (_Float16)x1.y;
      af[6] = (_Float16)x1.z; af[7] = (_Float16)x1.w;
#pragma unroll
      for (int nt = 0; nt < 4; ++nt)
        acc[nt] = __builtin_amdgcn_mfma_f32_16x16x32_f16(af, bf[nt * 4 + kk], acc[nt], 0, 0, 0);
    }
#pragma unroll
    for (int nt = 0; nt < 4; ++nt) {
#pragma unroll
      for (int r = 0; r < 4; ++r) {
        float val = acc[nt][r];
        float vd = val * a1d_l[nt];
        vd += __shfl_xor(vd, 1); vd += __shfl_xor(vd, 2); vd += __shfl_xor(vd, 4);
        int node = n0 + q * 4 + r;
        if (node < NN) {
          P1[((size_t)node << 6) + nt * 16 + c] = to_fp8(val);
          if ((c & 7) == 0) ed1[node * 8 + 2 * nt + (c >> 3)] = __float2half(vd);
        }
      }
    }
  }
}

// ---------------- CSR phase-2: gather the bucket's 196 runs into LDS,
//                  then histogram+scan+scatter + coalesced writeout ----------------

__global__ __launch_bounds__(256) void k_p2(const int* __restrict__ bcount,
                                            const int* __restrict__ bbuf,
                                            const int* __restrict__ tbl,
                                            int* __restrict__ offsets,
                                            int* __restrict__ edge_src) {
  __shared__ int stage[BCAP];          // 20.5 KB concat of this bucket's runs
  __shared__ int cnt[BKW];
  __shared__ int s1[BKW];
  __shared__ int cur[BKW];
  __shared__ int red[256];
  __shared__ int sorted[BCAP + BKW];   // 21 KB
  int b = blockIdx.x, tid = threadIdx.x;
  // inline exclusive prefix over buckets j < b of (bcount[j] + self-loops(j))
  int partial = 0;
  for (int j = tid; j < b; j += 256)
    partial += bcount[j] + min(BKW, NN - (j << 7));
  red[tid] = partial;
  __syncthreads();
  for (int off = 128; off >= 1; off >>= 1) {
    if (tid < off) red[tid] += red[tid + off];
    __syncthreads();
  }
  int base = red[0];
  __syncthreads();                     // red reused below
  // run descriptors: thread t < NB_P1 owns block t's run for bucket b
  int myexcl = 0, mycnt = 0;
  if (tid < NB_P1) {
    myexcl = tbl[tid * TROW + b];
    mycnt  = tbl[tid * TROW + b + 1] - myexcl;   // b+1 <= NBK; entry NBK = total
  }
  red[tid] = mycnt;                    // inclusive scan of run counts
  __syncthreads();
  for (int off = 1; off < 256; off <<= 1) {
    int v = (tid >= off) ? red[tid - off] : 0;
    __syncthreads();
    red[tid] += v;
    __syncthreads();
  }
  int n = red[255];                    // total edges this bucket (== bcount[b])
  int dstb = red[tid] - mycnt;
  if (tid < NB_P1) {
    const int* sb = bbuf + (size_t)tid * EPB + myexcl;
    for (int k = 0; k < mycnt; ++k) stage[dstb + k] = sb[k];
  }
  __syncthreads();
  int d0 = b << 7;
  int width = min(BKW, NN - d0);
  if (tid < BKW) cnt[tid] = (tid < width) ? 1 : 0;
  __syncthreads();
  for (int i = tid; i < n; i += 256) atomicAdd(&cnt[stage[i] & 127], 1);
  __syncthreads();
  if (tid < BKW) s1[tid] = cnt[tid];
  __syncthreads();
  for (int off = 1; off < BKW; off <<= 1) {
    int u = (tid < BKW && tid >= off) ? s1[tid - off] : 0;
    __syncthreads();
    if (tid < BKW) s1[tid] += u;
    __syncthreads();
  }
  if (tid < width) {
    int excl = s1[tid] - cnt[tid];
    offsets[d0 + tid] = base + excl;
    sorted[excl] = d0 + tid;          // self-loop first
    cur[tid] = excl + 1;
  }
  if (b == 0 && tid == 0) offsets[NN] = ET;
  __syncthreads();
  for (int i = tid; i < n; i += 256) {
    int p = stage[i];
    int pos = atomicAdd(&cur[p & 127], 1);
    sorted[pos] = p >> 7;             // LDS scatter (cheap)
  }
  __syncthreads();
  int m = n + width;
  for (int i = tid; i < m; i += 256)
    edge_src[base + i] = sorted[i];   // coalesced streaming writeout
}

// ---------------- Layer 1 aggregation: 8 dsts/wave, es recomputed from fp8,
//                  shuffle-shared src loads (round-9 proven form) ----------------

__global__ __launch_bounds__(256) void k_agg1(
    const int* __restrict__ offsets, const int* __restrict__ edge_src,
    const unsigned char* __restrict__ P1, const float* __restrict__ a1s,
    const __half* __restrict__ ed1, __half* __restrict__ x2) {
  int wv = threadIdx.x >> 6, lane = threadIdx.x & 63;
  int g = lane >> 3, p = lane & 7;        // group g: dst; lane p: head p, feats 8p..8p+7
  int gbase = lane & 56;                  // first lane of this group
  int dst = blockIdx.x * 32 + wv * 8 + g;
  float edv = __half2float(ed1[dst * 8 + p]);
  float4 as0 = *reinterpret_cast<const float4*>(a1s + p * 8);
  float4 as1 = *reinterpret_cast<const float4*>(a1s + p * 8 + 4);
  int beg = offsets[dst], end = offsets[dst + 1];
  int deg = end - beg;                    // >= 1 (self-loop)
  int md = deg;
#pragma unroll
  for (int o = 8; o < 64; o <<= 1) md = max(md, __shfl_xor(md, o, 64));
  float l = 0.f;
  float a[8] = {0.f, 0.f, 0.f, 0.f, 0.f, 0.f, 0.f, 0.f};
  for (int t = 0; t < md; t += 8) {
    // one src load per lane, broadcast across the group via shuffle
    int idx = t + p;
    int ci = beg + ((idx < deg) ? idx : (deg - 1));
    int mysrc = edge_src[ci];
    int src[8]; uint2 raw[8];
#pragma unroll
    for (int i = 0; i < 8; ++i) src[i] = __shfl(mysrc, gbase | i, 64);
#pragma unroll
    for (int i = 0; i < 8; ++i)
      raw[i] = *reinterpret_cast<const uint2*>(P1 + ((size_t)src[i] << 6) + (p << 3));
#pragma unroll
    for (int i = 0; i < 8; ++i) {
      v2f f01 = __builtin_amdgcn_cvt_pk_f32_fp8(raw[i].x, false);
      v2f f23 = __builtin_amdgcn_cvt_pk_f32_fp8(raw[i].x, true);
      v2f f45 = __builtin_amdgcn_cvt_pk_f32_fp8(raw[i].y, false);
      v2f f67 = __builtin_amdgcn_cvt_pk_f32_fp8(raw[i].y, true);
      // recompute e_src for head p from the fp8 fragment (bytes already in regs)
      float es = f01.x * as0.x + f01.y * as0.y + f23.x * as0.z + f23.y * as0.w
               + f45.x * as1.x + f45.y * as1.y + f67.x * as1.z + f67.y * as1.w;
      float e = lrelu(es + edv);
      float pr = (t + i < deg) ? __expf(e) : 0.f;   // |e|<3 provably: no max-shift
      l += pr;
      a[0] += pr * f01.x; a[1] += pr * f01.y;
      a[2] += pr * f23.x; a[3] += pr * f23.y;
      a[4] += pr * f45.x; a[5] += pr * f45.y;
      a[6] += pr * f67.x; a[7] += pr * f67.y;
    }
  }
  float rl = 1.f / l;
  union { __half h[8]; uint4 u; } pk;
#pragma unroll
  for (int i = 0; i < 8; ++i) {
    float v = a[i] * rl;
    v = (v > 0.f) ? v : (__expf(v) - 1.f);   // ELU fused
    pk.h[i] = __float2half(v);
  }
  *reinterpret_cast<uint4*>(x2 + ((size_t)dst << 6) + (p << 3)) = pk.u;
}

// ---------------- Layer 2: MFMA h2 = x2 @ W2 -> 64 B records (h fp8 @0..39, es fp16 @40) ----------------

__global__ __launch_bounds__(256) void k_gemm2(
    const __half* __restrict__ x2, const float* __restrict__ W2,
    const float* __restrict__ a2s, const float* __restrict__ a2d,
    unsigned char* __restrict__ P2, float* __restrict__ ed2) {
  __shared__ _Float16 Wb[6 * 64 * 8];   // 6 KB
  int tid = threadIdx.x;
  for (int idx = tid; idx < 6 * 64; idx += 256) {
    int f = idx >> 6, l = idx & 63;
    int nt = f >> 1, kk = f & 1;
    int ql = l >> 4, cl = l & 15;
    int col = nt * 16 + cl;
    int k0 = kk * 32 + ql * 8;
    v8h tmp;
#pragma unroll
    for (int j = 0; j < 8; ++j)
      tmp[j] = (col < 40) ? (_Float16)W2[(k0 + j) * 40 + col] : (_Float16)0.f;
    *reinterpret_cast<v8h*>(&Wb[idx * 8]) = tmp;
  }
  __syncthreads();
  int wv = tid >> 6, lane = tid & 63;
  int q = lane >> 4, c = lane & 15;
  v8h bf[6];
#pragma unroll
  for (int f = 0; f < 6; ++f)
    bf[f] = *reinterpret_cast<const v8h*>(&Wb[(f * 64 + lane) * 8]);
  float a2s_l[3], a2d_l[3];
#pragma unroll
  for (int nt = 0; nt < 3; ++nt) {
    int n = nt * 16 + c;
    a2s_l[nt] = (n < 40) ? a2s[n] : 0.f;
    a2d_l[nt] = (n < 40) ? a2d[n] : 0.f;
  }
  for (int t = 0; t < 4; ++t) {
    int n0 = blockIdx.x * 256 + wv * 64 + t * 16;
    int row = n0 + c;
    row = (row < NN) ? row : (NN - 1);
    v4f acc[3] = {{0.f,0.f,0.f,0.f},{0.f,0.f,0.f,0.f},{0.f,0.f,0.f,0.f}};
#pragma unroll
    for (int kk = 0; kk < 2; ++kk) {
      v8h af = *reinterpret_cast<const v8h*>(x2 + (size_t)row * 64 + kk * 32 + q * 8);
#pragma unroll
      for (int nt = 0; nt < 3; ++nt)
        acc[nt] = __builtin_amdgcn_mfma_f32_16x16x32_f16(af, bf[nt * 2 + kk], acc[nt], 0, 0, 0);
    }
#pragma unroll
    for (int r = 0; r < 4; ++r) {
      float v0 = acc[0][r], v1 = acc[1][r], v2 = acc[2][r];
      float s = v0 * a2s_l[0] + v1 * a2s_l[1] + v2 * a2s_l[2];
      float d = v0 * a2d_l[0] + v1 * a2d_l[1] + v2 * a2d_l[2];
      s += __shfl_xor(s, 1); s += __shfl_xor(s, 2); s += __shfl_xor(s, 4); s += __shfl_xor(s, 8);
      d += __shfl_xor(d, 1); d += __shfl_xor(d, 2); d += __shfl_xor(d, 4); d += __shfl_xor(d, 8);
      int node = n0 + q * 4 + r;
      if (node < NN) {
        unsigned char* rec = P2 + ((size_t)node << 6);
        if (c < 8) rec[32 + c] = to_fp8(v2);          // nt=2: classes 32..39
        rec[c]      = to_fp8(v0);                     // nt=0: classes 0..15
        rec[16 + c] = to_fp8(v1);                     // nt=1: classes 16..31
        if (c == 0) {
          *reinterpret_cast<__half*>(rec + 40) = __float2half(s);
          ed2[node] = d;
        }
      }
    }
  }
}

// ---------------- Layer 2 aggregation + log_softmax: 8 dsts/wave x 8 lanes ----------------
// exp-dedup (me = p) + shuffle-shared src loads (round-9 proven form).

__global__ __launch_bounds__(256) void k_agg2(
    const int* __restrict__ offsets, const int* __restrict__ edge_src,
    const unsigned char* __restrict__ P2, const float* __restrict__ ed2,
    float* __restrict__ out) {
  int wv = threadIdx.x >> 6, lane = threadIdx.x & 63;
  int g = lane >> 3, p = lane & 7;    // group g: dst; lane p: classes 8p..8p+7 (p<5)
  bool act = p < 5;
  int cp = act ? p : 0;
  int dst = blockIdx.x * 32 + wv * 8 + g;
  float edv = ed2[dst];
  int beg = offsets[dst], end = offsets[dst + 1];
  int deg = end - beg;
  int md = deg;
#pragma unroll
  for (int o = 8; o < 64; o <<= 1) md = max(md, __shfl_xor(md, o, 64));
  int gbase = lane & 56;              // first lane of this group
  float l = 0.f;
  float a[8] = {0.f, 0.f, 0.f, 0.f, 0.f, 0.f, 0.f, 0.f};
  for (int t = 0; t < md; t += 8) {
    // one src load per lane, broadcast across the group via shuffle
    int idx = t + p;
    int ci = beg + ((idx < deg) ? idx : (deg - 1));
    int mysrc = edge_src[ci];
    int src[8]; uint2 raw[8];
#pragma unroll
    for (int i = 0; i < 8; ++i) src[i] = __shfl(mysrc, gbase | i, 64);
    // one es-load + one exp chain per lane, covering edge p of this group
    float myes = __half2float(*reinterpret_cast<const __half*>(
        P2 + ((size_t)mysrc << 6) + 40));
    float mye = lrelu(myes + edv);
    float mypr = (t + p < deg) ? __expf(mye) : 0.f;
#pragma unroll
    for (int i = 0; i < 8; ++i)
      raw[i] = *reinterpret_cast<const uint2*>(P2 + ((size_t)src[i] << 6) + (cp << 3));
#pragma unroll
    for (int i = 0; i < 8; ++i) {
      float pr = __shfl(mypr, gbase | i, 64);
      v2f f01 = __builtin_amdgcn_cvt_pk_f32_fp8(raw[i].x, false);
      v2f f23 = __builtin_amdgcn_cvt_pk_f32_fp8(raw[i].x, true);
      v2f f45 = __builtin_amdgcn_cvt_pk_f32_fp8(raw[i].y, false);
      v2f f67 = __builtin_amdgcn_cvt_pk_f32_fp8(raw[i].y, true);
      l += pr;
      a[0] += pr * f01.x; a[1] += pr * f01.y;
      a[2] += pr * f23.x; a[3] += pr * f23.y;
      a[4] += pr * f45.x; a[5] += pr * f45.y;
      a[6] += pr * f67.x; a[7] += pr * f67.y;
    }
  }
  float rl = 1.f / l;
  float v[8];
#pragma unroll
  for (int j = 0; j < 8; ++j) v[j] = a[j] * rl;
  float red = act ? fmaxf(fmaxf(fmaxf(v[0], v[1]), fmaxf(v[2], v[3])),
                          fmaxf(fmaxf(v[4], v[5]), fmaxf(v[6], v[7])))
                  : -INFINITY;
#pragma unroll
  for (int o = 1; o < 8; o <<= 1) red = fmaxf(red, __shfl_xor(red, o, 64));
  float se = 0.f;
  if (act) {
#pragma unroll
    for (int j = 0; j < 8; ++j) se += __expf(v[j] - red);
  }
#pragma unroll
  for (int o = 1; o < 8; o <<= 1) se += __shfl_xor(se, o, 64);
  float ls = red + __logf(se);
  if (act) {
    float* op = out + (size_t)dst * 40 + (p << 3);
    *reinterpret_cast<float4*>(op) =
        make_float4(v[0] - ls, v[1] - ls, v[2] - ls, v[3] - ls);
    *reinterpret_cast<float4*>(op + 4) =
        make_float4(v[4] - ls, v[5] - ls, v[6] - ls, v[7] - ls);
  }
}

// ---------------- launch ----------------

extern "C" void kernel_launch(void* const* d_in, const int* in_sizes, int n_in,
                              void* d_out, int out_size, void* d_ws, size_t ws_size,
                              hipStream_t stream) {
  const float* x   = (const float*)d_in[0];
  const int*   adj = (const int*)d_in[1];     // [2, EE]
  const float* W1  = (const float*)d_in[2];
  const float* a1s = (const float*)d_in[3];
  const float* a1d = (const float*)d_in[4];
  const float* W2  = (const float*)d_in[5];
  const float* a2s = (const float*)d_in[6];
  const float* a2d = (const float*)d_in[7];
  float* out = (float*)d_out;

  const int* srcs = adj;
  const int* dsts = adj + EE;

  char* w = (char*)d_ws;
  size_t off = 0;
  auto alloc = [&](size_t bytes) -> void* {
    void* p = w + off;
    off = (off + bytes + 255) & ~(size_t)255;
    return p;
  };
  int* offsets      = (int*)alloc((size_t)(NN + 1) * 4);
  int* edge_src     = (int*)alloc((size_t)ET * 4);
  int* bcount       = (int*)alloc((size_t)NBK * 4);
  unsigned char* P1 = (unsigned char*)alloc((size_t)NN * 64);  // 6.4 MB fp8 h, 64 B/line recs
  __half* ed1       = (__half*)alloc((size_t)NN * 8 * 2);      // 1.6 MB fp16
  __half* x2        = (__half*)alloc((size_t)NN * 64 * 2);     // 12.8 MB
  int* bbuf         = (int*)alloc((size_t)NBK * BCAP * 4);     // 16 MB (same size)
  // block-major edges use NB_P1*EPB = 3,211,264 ints of bbuf; the run table
  // (NB_P1*TROW = 153,468 ints) is carved from bbuf's slack -> layout unchanged.
  int* tbl = bbuf + (size_t)NB_P1 * EPB;
  // layer-2 buffers alias layer-1 (P1/ed1 dead after k_agg1):
  unsigned char* P2 = P1;     // 6.4 MB == 6.4 MB
  float* ed2 = (float*)ed1;   // 400 KB < 1.6 MB

  hipMemsetAsync(bcount, 0, (size_t)NBK * 4, stream);
  k_p1g1<<<NB_P1 + NB_G, 256, 0, stream>>>(srcs, dsts, bcount, bbuf, tbl,
                                           x, W1, a1d, P1, ed1);
  k_p2<<<NBK, 256, 0, stream>>>(bcount, bbuf, tbl, offsets, edge_src);

  k_agg1<<<NN / 32, 256, 0, stream>>>(offsets, edge_src, P1, a1s, ed1, x2);
  k_gemm2<<<NB_G, 256, 0, stream>>>(x2, W2, a2s, a2d, P2, ed2);
  k_agg2<<<NN / 32, 256, 0, stream>>>(offsets, edge_src, P2, ed2, out);
}

// Round 15
// 284.661 us; speedup vs baseline: 1.0216x; 1.0216x over previous
//
#include <hip/hip_runtime.h>
#include <hip/hip_fp16.h>
#include <math.h>

#define NN 100000
#define EE 3200000
#define ET (EE + NN)
#define BKW 128                       // dsts per bucket
#define NBK ((NN + BKW - 1) / BKW)    // 782 buckets
#define BCAP 5120                     // per-bucket capacity
#define EPB 4096                      // edges per p1 block (782 blocks)
#define NB_P1 ((EE + EPB - 1) / EPB)  // 782
#define NB_G 391                      // gemm blocks: 391*256 = 100096 >= NN

typedef float v2f __attribute__((ext_vector_type(2)));
typedef float v4f __attribute__((ext_vector_type(4)));
typedef _Float16 v8h __attribute__((ext_vector_type(8)));

__device__ __forceinline__ float lrelu(float v) { return fmaxf(v, 0.2f * v); }

__device__ __forceinline__ unsigned char to_fp8(float v) {
  return (unsigned char)(__builtin_amdgcn_cvt_pk_fp8_f32(v, v, 0, false) & 0xff);
}

// ---------------- Fused: CSR phase-1 bucket sort (blocks 0..NB_P1-1)
//                  + Layer-1 MFMA GEMM (blocks NB_P1..NB_P1+NB_G-1) ----------------
// p1 LDS-sorts its 4096 edges by bucket before writing, so the global scatter
// becomes coalesced runs (~5.2 edges/run). Round-14's fully-streaming
// block-major variant shifted the cost to p2 (+WRITE RMW from gemm1 L2
// contention) — this round-13 form is the measured best (284.9 us total).
// gemm1 D layout (16x16x32): row = (lane>>4)*4 + reg, col = lane&15.

__global__ __launch_bounds__(256) void k_p1g1(
    const int* __restrict__ srcs, const int* __restrict__ dsts,
    int* __restrict__ bcount, int* __restrict__ bbuf,
    const float* __restrict__ x, const float* __restrict__ W1,
    const float* __restrict__ a1d,
    unsigned char* __restrict__ P1, __half* __restrict__ ed1) {
  __shared__ int spk[EPB];            // 16 KB sorted pk  (g1 aliases as Wb)
  __shared__ short sbkt[EPB];         // 8 KB bucket id per sorted slot
  __shared__ int lcnt[NBK];           // per-bucket count
  __shared__ int excl[NBK];           // exclusive prefix within block
  __shared__ int gbase[NBK];          // global base per bucket
  __shared__ int partials[256];
  int tid = threadIdx.x;
  if (blockIdx.x < NB_P1) {
    int e0 = blockIdx.x * EPB;
    int m = min(EPB, EE - e0);        // multiple of 16
    for (int i = tid; i < NBK; i += 256) lcnt[i] = 0;
    __syncthreads();
    bool valid = (tid * 16) < m;
    int rank[16], bkt[16], pk[16];
    if (valid) {
      const int4* dp = reinterpret_cast<const int4*>(dsts + e0 + tid * 16);
      const int4* sp = reinterpret_cast<const int4*>(srcs + e0 + tid * 16);
      int4 d4[4], s4[4];
#pragma unroll
      for (int i = 0; i < 4; ++i) { d4[i] = dp[i]; s4[i] = sp[i]; }
#pragma unroll
      for (int i = 0; i < 16; ++i) {
        int d = ((const int*)d4)[i];
        int s = ((const int*)s4)[i];
        int b = d >> 7;
        rank[i] = atomicAdd(&lcnt[b], 1);
        bkt[i] = b;
        pk[i] = (s << 7) | (d & 127);
      }
    }
    __syncthreads();
    // blocked exclusive scan over NBK buckets (4 buckets/thread)
    int b0 = tid * 4;
    int own = 0;
#pragma unroll
    for (int k = 0; k < 4; ++k) {
      int b = b0 + k;
      if (b < NBK) own += lcnt[b];
    }
    partials[tid] = own;
    __syncthreads();
    for (int off = 1; off < 256; off <<= 1) {
      int v = (tid >= off) ? partials[tid - off] : 0;
      __syncthreads();
      partials[tid] += v;
      __syncthreads();
    }
    int run = partials[tid] - own;    // exclusive base of my bucket range
#pragma unroll
    for (int k = 0; k < 4; ++k) {
      int b = b0 + k;
      if (b < NBK) {
        excl[b] = run;
        run += lcnt[b];
      }
    }
    // global allocation per bucket
    for (int i = tid; i < NBK; i += 256) {
      int c = lcnt[i];
      gbase[i] = c ? atomicAdd(&bcount[i], c) : 0;
    }
    __syncthreads();
    // scatter into sorted LDS array (LDS pipe, cheap)
    if (valid) {
#pragma unroll
      for (int i = 0; i < 16; ++i) {
        int j = excl[bkt[i]] + rank[i];
        spk[j] = pk[i];
        sbkt[j] = (short)bkt[i];
      }
    }
    __syncthreads();
    // coalesced-run copy out: consecutive lanes write consecutive slots
    for (int j = tid; j < m; j += 256) {
      int b = sbkt[j];
      bbuf[(size_t)b * BCAP + gbase[b] + (j - excl[b])] = spk[j];
    }
    return;
  }
  // ---- gemm1 ----
  _Float16* Wb = (_Float16*)spk;   // 16 KB fragment-major (alias)
  int gbid = blockIdx.x - NB_P1;
  for (int idx = tid; idx < 16 * 64; idx += 256) {
    int f = idx >> 6, l = idx & 63;
    int nt = f >> 2, kk = f & 3;
    int ql = l >> 4, cl = l & 15;
    int col = nt * 16 + cl;
    int k0 = kk * 32 + ql * 8;
    v8h tmp;
#pragma unroll
    for (int j = 0; j < 8; ++j) tmp[j] = (_Float16)W1[(k0 + j) * 64 + col];
    *reinterpret_cast<v8h*>(&Wb[idx * 8]) = tmp;
  }
  __syncthreads();
  int wv = tid >> 6, lane = tid & 63;
  int q = lane >> 4, c = lane & 15;
  v8h bf[16];
#pragma unroll
  for (int f = 0; f < 16; ++f)
    bf[f] = *reinterpret_cast<const v8h*>(&Wb[(f * 64 + lane) * 8]);
  float a1d_l[4];
#pragma unroll
  for (int nt = 0; nt < 4; ++nt) a1d_l[nt] = a1d[nt * 16 + c];
  for (int t = 0; t < 4; ++t) {
    int n0 = gbid * 256 + wv * 64 + t * 16;
    int row = n0 + c;
    row = (row < NN) ? row : (NN - 1);
    v4f acc[4] = {{0.f,0.f,0.f,0.f},{0.f,0.f,0.f,0.f},{0.f,0.f,0.f,0.f},{0.f,0.f,0.f,0.f}};
#pragma unroll
    for (int kk = 0; kk < 4; ++kk) {
      const float* xp = x + (size_t)row * 128 + kk * 32 + q * 8;
      float4 x0 = *reinterpret_cast<const float4*>(xp);
      float4 x1 = *reinterpret_cast<const float4*>(xp + 4);
      v8h af;
      af[0] = (_Float16)x0.x; af[1] = (_Float16)x0.y;
      af[2] = (_Float16)x0.z; af[3] = (_Float16)x0.w;
      af[4] = (_Float16)x1.x; af[5] = (_Float16)x1.y;
      af[6] = (_Float16)x1.z; af[7] = (_Float16)x1.w;
#pragma unroll
      for (int nt = 0; nt < 4; ++nt)
        acc[nt] = __builtin_amdgcn_mfma_f32_16x16x32_f16(af, bf[nt * 4 + kk], acc[nt], 0, 0, 0);
    }
#pragma unroll
    for (int nt = 0; nt < 4; ++nt) {
#pragma unroll
      for (int r = 0; r < 4; ++r) {
        float val = acc[nt][r];
        float vd = val * a1d_l[nt];
        vd += __shfl_xor(vd, 1); vd += __shfl_xor(vd, 2); vd += __shfl_xor(vd, 4);
        int node = n0 + q * 4 + r;
        if (node < NN) {
          P1[((size_t)node << 6) + nt * 16 + c] = to_fp8(val);
          if ((c & 7) == 0) ed1[node * 8 + 2 * nt + (c >> 3)] = __float2half(vd);
        }
      }
    }
  }
}

// ---------------- CSR phase-2: per-bucket histogram+scan, LDS-staged sort,
//                  coalesced streaming writeout ----------------

__global__ __launch_bounds__(256) void k_p2(const int* __restrict__ bcount,
                                            const int* __restrict__ bbuf,
                                            int* __restrict__ offsets,
                                            int* __restrict__ edge_src) {
  __shared__ int cnt[BKW];
  __shared__ int s1[BKW];
  __shared__ int cur[BKW];
  __shared__ int red[256];
  __shared__ int sorted[BCAP + BKW];   // 5248 ints = 21 KB
  int b = blockIdx.x, tid = threadIdx.x;
  // inline exclusive prefix over buckets j < b of (bcount[j] + self-loops(j))
  int partial = 0;
  for (int j = tid; j < b; j += 256)
    partial += bcount[j] + min(BKW, NN - (j << 7));
  red[tid] = partial;
  __syncthreads();
  for (int off = 128; off >= 1; off >>= 1) {
    if (tid < off) red[tid] += red[tid + off];
    __syncthreads();
  }
  int base = red[0];
  int d0 = b << 7;
  int width = min(BKW, NN - d0);
  int n = bcount[b];
  const int* buf = bbuf + (size_t)b * BCAP;
  if (tid < BKW) cnt[tid] = (tid < width) ? 1 : 0;
  __syncthreads();
  for (int i = tid; i < n; i += 256) atomicAdd(&cnt[buf[i] & 127], 1);
  __syncthreads();
  if (tid < BKW) s1[tid] = cnt[tid];
  __syncthreads();
  for (int off = 1; off < BKW; off <<= 1) {
    int u = (tid < BKW && tid >= off) ? s1[tid - off] : 0;
    __syncthreads();
    if (tid < BKW) s1[tid] += u;
    __syncthreads();
  }
  if (tid < width) {
    int excl = s1[tid] - cnt[tid];
    offsets[d0 + tid] = base + excl;
    sorted[excl] = d0 + tid;          // self-loop first
    cur[tid] = excl + 1;
  }
  if (b == 0 && tid == 0) offsets[NN] = ET;
  __syncthreads();
  for (int i = tid; i < n; i += 256) {
    int p = buf[i];
    int pos = atomicAdd(&cur[p & 127], 1);
    sorted[pos] = p >> 7;             // LDS scatter (cheap)
  }
  __syncthreads();
  int m = n + width;
  for (int i = tid; i < m; i += 256)
    edge_src[base + i] = sorted[i];   // coalesced streaming writeout
}

// ---------------- Layer 1 aggregation: 8 dsts/wave, es recomputed from fp8,
//                  shuffle-shared src loads (round-9 proven form) ----------------

__global__ __launch_bounds__(256) void k_agg1(
    const int* __restrict__ offsets, const int* __restrict__ edge_src,
    const unsigned char* __restrict__ P1, const float* __restrict__ a1s,
    const __half* __restrict__ ed1, __half* __restrict__ x2) {
  int wv = threadIdx.x >> 6, lane = threadIdx.x & 63;
  int g = lane >> 3, p = lane & 7;        // group g: dst; lane p: head p, feats 8p..8p+7
  int gbase = lane & 56;                  // first lane of this group
  int dst = blockIdx.x * 32 + wv * 8 + g;
  float edv = __half2float(ed1[dst * 8 + p]);
  float4 as0 = *reinterpret_cast<const float4*>(a1s + p * 8);
  float4 as1 = *reinterpret_cast<const float4*>(a1s + p * 8 + 4);
  int beg = offsets[dst], end = offsets[dst + 1];
  int deg = end - beg;                    // >= 1 (self-loop)
  int md = deg;
#pragma unroll
  for (int o = 8; o < 64; o <<= 1) md = max(md, __shfl_xor(md, o, 64));
  float l = 0.f;
  float a[8] = {0.f, 0.f, 0.f, 0.f, 0.f, 0.f, 0.f, 0.f};
  for (int t = 0; t < md; t += 8) {
    // one src load per lane, broadcast across the group via shuffle
    int idx = t + p;
    int ci = beg + ((idx < deg) ? idx : (deg - 1));
    int mysrc = edge_src[ci];
    int src[8]; uint2 raw[8];
#pragma unroll
    for (int i = 0; i < 8; ++i) src[i] = __shfl(mysrc, gbase | i, 64);
#pragma unroll
    for (int i = 0; i < 8; ++i)
      raw[i] = *reinterpret_cast<const uint2*>(P1 + ((size_t)src[i] << 6) + (p << 3));
#pragma unroll
    for (int i = 0; i < 8; ++i) {
      v2f f01 = __builtin_amdgcn_cvt_pk_f32_fp8(raw[i].x, false);
      v2f f23 = __builtin_amdgcn_cvt_pk_f32_fp8(raw[i].x, true);
      v2f f45 = __builtin_amdgcn_cvt_pk_f32_fp8(raw[i].y, false);
      v2f f67 = __builtin_amdgcn_cvt_pk_f32_fp8(raw[i].y, true);
      // recompute e_src for head p from the fp8 fragment (bytes already in regs)
      float es = f01.x * as0.x + f01.y * as0.y + f23.x * as0.z + f23.y * as0.w
               + f45.x * as1.x + f45.y * as1.y + f67.x * as1.z + f67.y * as1.w;
      float e = lrelu(es + edv);
      float pr = (t + i < deg) ? __expf(e) : 0.f;   // |e|<3 provably: no max-shift
      l += pr;
      a[0] += pr * f01.x; a[1] += pr * f01.y;
      a[2] += pr * f23.x; a[3] += pr * f23.y;
      a[4] += pr * f45.x; a[5] += pr * f45.y;
      a[6] += pr * f67.x; a[7] += pr * f67.y;
    }
  }
  float rl = 1.f / l;
  union { __half h[8]; uint4 u; } pk;
#pragma unroll
  for (int i = 0; i < 8; ++i) {
    float v = a[i] * rl;
    v = (v > 0.f) ? v : (__expf(v) - 1.f);   // ELU fused
    pk.h[i] = __float2half(v);
  }
  *reinterpret_cast<uint4*>(x2 + ((size_t)dst << 6) + (p << 3)) = pk.u;
}

// ---------------- Layer 2: MFMA h2 = x2 @ W2 -> 64 B records (h fp8 @0..39, es fp16 @40) ----------------

__global__ __launch_bounds__(256) void k_gemm2(
    const __half* __restrict__ x2, const float* __restrict__ W2,
    const float* __restrict__ a2s, const float* __restrict__ a2d,
    unsigned char* __restrict__ P2, float* __restrict__ ed2) {
  __shared__ _Float16 Wb[6 * 64 * 8];   // 6 KB
  int tid = threadIdx.x;
  for (int idx = tid; idx < 6 * 64; idx += 256) {
    int f = idx >> 6, l = idx & 63;
    int nt = f >> 1, kk = f & 1;
    int ql = l >> 4, cl = l & 15;
    int col = nt * 16 + cl;
    int k0 = kk * 32 + ql * 8;
    v8h tmp;
#pragma unroll
    for (int j = 0; j < 8; ++j)
      tmp[j] = (col < 40) ? (_Float16)W2[(k0 + j) * 40 + col] : (_Float16)0.f;
    *reinterpret_cast<v8h*>(&Wb[idx * 8]) = tmp;
  }
  __syncthreads();
  int wv = tid >> 6, lane = tid & 63;
  int q = lane >> 4, c = lane & 15;
  v8h bf[6];
#pragma unroll
  for (int f = 0; f < 6; ++f)
    bf[f] = *reinterpret_cast<const v8h*>(&Wb[(f * 64 + lane) * 8]);
  float a2s_l[3], a2d_l[3];
#pragma unroll
  for (int nt = 0; nt < 3; ++nt) {
    int n = nt * 16 + c;
    a2s_l[nt] = (n < 40) ? a2s[n] : 0.f;
    a2d_l[nt] = (n < 40) ? a2d[n] : 0.f;
  }
  for (int t = 0; t < 4; ++t) {
    int n0 = blockIdx.x * 256 + wv * 64 + t * 16;
    int row = n0 + c;
    row = (row < NN) ? row : (NN - 1);
    v4f acc[3] = {{0.f,0.f,0.f,0.f},{0.f,0.f,0.f,0.f},{0.f,0.f,0.f,0.f}};
#pragma unroll
    for (int kk = 0; kk < 2; ++kk) {
      v8h af = *reinterpret_cast<const v8h*>(x2 + (size_t)row * 64 + kk * 32 + q * 8);
#pragma unroll
      for (int nt = 0; nt < 3; ++nt)
        acc[nt] = __builtin_amdgcn_mfma_f32_16x16x32_f16(af, bf[nt * 2 + kk], acc[nt], 0, 0, 0);
    }
#pragma unroll
    for (int r = 0; r < 4; ++r) {
      float v0 = acc[0][r], v1 = acc[1][r], v2 = acc[2][r];
      float s = v0 * a2s_l[0] + v1 * a2s_l[1] + v2 * a2s_l[2];
      float d = v0 * a2d_l[0] + v1 * a2d_l[1] + v2 * a2d_l[2];
      s += __shfl_xor(s, 1); s += __shfl_xor(s, 2); s += __shfl_xor(s, 4); s += __shfl_xor(s, 8);
      d += __shfl_xor(d, 1); d += __shfl_xor(d, 2); d += __shfl_xor(d, 4); d += __shfl_xor(d, 8);
      int node = n0 + q * 4 + r;
      if (node < NN) {
        unsigned char* rec = P2 + ((size_t)node << 6);
        if (c < 8) rec[32 + c] = to_fp8(v2);          // nt=2: classes 32..39
        rec[c]      = to_fp8(v0);                     // nt=0: classes 0..15
        rec[16 + c] = to_fp8(v1);                     // nt=1: classes 16..31
        if (c == 0) {
          *reinterpret_cast<__half*>(rec + 40) = __float2half(s);
          ed2[node] = d;
        }
      }
    }
  }
}

// ---------------- Layer 2 aggregation + log_softmax: 8 dsts/wave x 8 lanes ----------------
// exp-dedup (me = p) + shuffle-shared src loads (round-9 proven form).

__global__ __launch_bounds__(256) void k_agg2(
    const int* __restrict__ offsets, const int* __restrict__ edge_src,
    const unsigned char* __restrict__ P2, const float* __restrict__ ed2,
    float* __restrict__ out) {
  int wv = threadIdx.x >> 6, lane = threadIdx.x & 63;
  int g = lane >> 3, p = lane & 7;    // group g: dst; lane p: classes 8p..8p+7 (p<5)
  bool act = p < 5;
  int cp = act ? p : 0;
  int dst = blockIdx.x * 32 + wv * 8 + g;
  float edv = ed2[dst];
  int beg = offsets[dst], end = offsets[dst + 1];
  int deg = end - beg;
  int md = deg;
#pragma unroll
  for (int o = 8; o < 64; o <<= 1) md = max(md, __shfl_xor(md, o, 64));
  int gbase = lane & 56;              // first lane of this group
  float l = 0.f;
  float a[8] = {0.f, 0.f, 0.f, 0.f, 0.f, 0.f, 0.f, 0.f};
  for (int t = 0; t < md; t += 8) {
    // one src load per lane, broadcast across the group via shuffle
    int idx = t + p;
    int ci = beg + ((idx < deg) ? idx : (deg - 1));
    int mysrc = edge_src[ci];
    int src[8]; uint2 raw[8];
#pragma unroll
    for (int i = 0; i < 8; ++i) src[i] = __shfl(mysrc, gbase | i, 64);
    // one es-load + one exp chain per lane, covering edge p of this group
    float myes = __half2float(*reinterpret_cast<const __half*>(
        P2 + ((size_t)mysrc << 6) + 40));
    float mye = lrelu(myes + edv);
    float mypr = (t + p < deg) ? __expf(mye) : 0.f;
#pragma unroll
    for (int i = 0; i < 8; ++i)
      raw[i] = *reinterpret_cast<const uint2*>(P2 + ((size_t)src[i] << 6) + (cp << 3));
#pragma unroll
    for (int i = 0; i < 8; ++i) {
      float pr = __shfl(mypr, gbase | i, 64);
      v2f f01 = __builtin_amdgcn_cvt_pk_f32_fp8(raw[i].x, false);
      v2f f23 = __builtin_amdgcn_cvt_pk_f32_fp8(raw[i].x, true);
      v2f f45 = __builtin_amdgcn_cvt_pk_f32_fp8(raw[i].y, false);
      v2f f67 = __builtin_amdgcn_cvt_pk_f32_fp8(raw[i].y, true);
      l += pr;
      a[0] += pr * f01.x; a[1] += pr * f01.y;
      a[2] += pr * f23.x; a[3] += pr * f23.y;
      a[4] += pr * f45.x; a[5] += pr * f45.y;
      a[6] += pr * f67.x; a[7] += pr * f67.y;
    }
  }
  float rl = 1.f / l;
  float v[8];
#pragma unroll
  for (int j = 0; j < 8; ++j) v[j] = a[j] * rl;
  float red = act ? fmaxf(fmaxf(fmaxf(v[0], v[1]), fmaxf(v[2], v[3])),
                          fmaxf(fmaxf(v[4], v[5]), fmaxf(v[6], v[7])))
                  : -INFINITY;
#pragma unroll
  for (int o = 1; o < 8; o <<= 1) red = fmaxf(red, __shfl_xor(red, o, 64));
  float se = 0.f;
  if (act) {
#pragma unroll
    for (int j = 0; j < 8; ++j) se += __expf(v[j] - red);
  }
#pragma unroll
  for (int o = 1; o < 8; o <<= 1) se += __shfl_xor(se, o, 64);
  float ls = red + __logf(se);
  if (act) {
    float* op = out + (size_t)dst * 40 + (p << 3);
    *reinterpret_cast<float4*>(op) =
        make_float4(v[0] - ls, v[1] - ls, v[2] - ls, v[3] - ls);
    *reinterpret_cast<float4*>(op + 4) =
        make_float4(v[4] - ls, v[5] - ls, v[6] - ls, v[7] - ls);
  }
}

// ---------------- launch ----------------

extern "C" void kernel_launch(void* const* d_in, const int* in_sizes, int n_in,
                              void* d_out, int out_size, void* d_ws, size_t ws_size,
                              hipStream_t stream) {
  const float* x   = (const float*)d_in[0];
  const int*   adj = (const int*)d_in[1];     // [2, EE]
  const float* W1  = (const float*)d_in[2];
  const float* a1s = (const float*)d_in[3];
  const float* a1d = (const float*)d_in[4];
  const float* W2  = (const float*)d_in[5];
  const float* a2s = (const float*)d_in[6];
  const float* a2d = (const float*)d_in[7];
  float* out = (float*)d_out;

  const int* srcs = adj;
  const int* dsts = adj + EE;

  char* w = (char*)d_ws;
  size_t off = 0;
  auto alloc = [&](size_t bytes) -> void* {
    void* p = w + off;
    off = (off + bytes + 255) & ~(size_t)255;
    return p;
  };
  int* offsets      = (int*)alloc((size_t)(NN + 1) * 4);
  int* edge_src     = (int*)alloc((size_t)ET * 4);
  int* bcount       = (int*)alloc((size_t)NBK * 4);
  unsigned char* P1 = (unsigned char*)alloc((size_t)NN * 64);  // 6.4 MB fp8 h, 64 B/line recs
  __half* ed1       = (__half*)alloc((size_t)NN * 8 * 2);      // 1.6 MB fp16
  __half* x2        = (__half*)alloc((size_t)NN * 64 * 2);     // 12.8 MB
  int* bbuf         = (int*)alloc((size_t)NBK * BCAP * 4);     // 16 MB
  // layer-2 buffers alias layer-1 (P1/ed1 dead after k_agg1):
  unsigned char* P2 = P1;     // 6.4 MB == 6.4 MB
  float* ed2 = (float*)ed1;   // 400 KB < 1.6 MB

  hipMemsetAsync(bcount, 0, (size_t)NBK * 4, stream);
  k_p1g1<<<NB_P1 + NB_G, 256, 0, stream>>>(srcs, dsts, bcount, bbuf,
                                           x, W1, a1d, P1, ed1);
  k_p2<<<NBK, 256, 0, stream>>>(bcount, bbuf, offsets, edge_src);

  k_agg1<<<NN / 32, 256, 0, stream>>>(offsets, edge_src, P1, a1s, ed1, x2);
  k_gemm2<<<NB_G, 256, 0, stream>>>(x2, W2, a2s, a2d, P2, ed2);
  k_agg2<<<NN / 32, 256, 0, stream>>>(offsets, edge_src, P2, ed2, out);
}